// Round 3
// baseline (448.689 us; speedup 1.0000x reference)
//
#include <hip/hip_runtime.h>

// LoKr: out = x @ (W + 2*scalar*(A kron B))^T  with B (16,1)
// => out[m,r] = (x@W^T)[m,r] + 2*scalar*B[r&15] * (x@A^T)[m, r>>4]
//
// R5: LDS-staged streaming GEMM (R4 was vector-memory-issue bound: per-lane
// 16-row gathers serialized the TA at ~6.5K cyc/step vs 800 budget).
//  - grid 256 x 512 threads. Block b owns out cols [32b,32b+32), full K.
//  - Waves split m 8-way: wave w = rows [16w,16w+16). acc = 12 regs. Each
//    wave stores its own out rows: no partials, no reduce kernel.
//  - x (bf16, L2-resident): global_load_lds, 1KB contiguous per instr,
//    linear LDS dest + XOR-swizzled SOURCE chunks (chunk c -> c^(row&7));
//    reader applies the same XOR -> conflict-free ds_read_b128 frags.
//  - W: reg-staged contiguously (thread t -> row t>>4, 512B segments),
//    fp32->bf16 converted once at stage, ds_write to padded 144B-stride
//    LDS (2-way bank rotation = free). A rows 2b,2b+1 ride along as LDS
//    rows 32,33; y2 via broadcast-A MFMA, extracted with one shfl.
//  - Single barrier per BK=64 step: W-LDS double-buffered, x double-
//    buffered, W regs 2-deep -> every load in flight ~1 full iteration
//    before the barrier that drains it (~850cy ~ HBM latency).

#define M_DIM 128
#define N_DIM 8192
#define K_DIM 8192
#define BN 32
#define BK 64
#define NSTEP (K_DIM / BK)   // 128

typedef __attribute__((ext_vector_type(8))) short bf16x8;   // 8 bf16 = 4 VGPRs
typedef __attribute__((ext_vector_type(4))) float f32x4;    // MFMA acc

__device__ __forceinline__ unsigned short f2bf(float f) {
  unsigned u = __builtin_bit_cast(unsigned, f);
  u += 0x7FFFu + ((u >> 16) & 1u);   // round-to-nearest-even
  return (unsigned short)(u >> 16);
}

__global__ void convert_x_kernel(const float4* __restrict__ x4,
                                 ushort4* __restrict__ xb4) {
  int t = blockIdx.x * blockDim.x + threadIdx.x;
  const int n4 = M_DIM * K_DIM / 4;  // 262144
  for (int i = t; i < n4; i += gridDim.x * blockDim.x) {
    float4 v = x4[i];
    ushort4 o;
    o.x = f2bf(v.x); o.y = f2bf(v.y); o.z = f2bf(v.z); o.w = f2bf(v.w);
    xb4[i] = o;
  }
}

// stage x tile (16KB) for k-offset KOFF into buffer BUF: 2 chunks of 1KB per wave
#define GLDS2(KOFF, BUF) { \
    __builtin_amdgcn_global_load_lds( \
        (const __attribute__((address_space(1))) unsigned int*)(xs0 + (KOFF)), \
        (__attribute__((address_space(3))) unsigned int*)(&xls[BUF][wv * 1024]), 16, 0, 0); \
    __builtin_amdgcn_global_load_lds( \
        (const __attribute__((address_space(1))) unsigned int*)(xs1 + (KOFF)), \
        (__attribute__((address_space(3))) unsigned int*)(&xls[BUF][wv * 1024 + 512]), 16, 0, 0); \
  }

// one BK=64 K-step. BF = compile-time parity. WREG/AREG hold fp32 tile S
// (loaded two iterations ago -> already drained, zero-stall convert).
#define ITER(S, BF, WREG, AREG) { \
    { ushort4 o; o.x = f2bf(WREG.x); o.y = f2bf(WREG.y); \
      o.z = f2bf(WREG.z); o.w = f2bf(WREG.w); \
      *(ushort4*)&wls[BF][t >> 4][(t & 15) * 4] = o; } \
    if (aact) { ushort2 o2; o2.x = f2bf(AREG.x); o2.y = f2bf(AREG.y); \
      *(ushort2*)&wls[BF][32 + (t >> 5)][(t & 31) * 2] = o2; } \
    __syncthreads();  /* wls[BF] + xls[BF] ready; drains in-flight loads */ \
    { int kn = ((S) + 2 < NSTEP ? (S) + 2 : NSTEP - 1) * BK; \
      WREG = *(const float4*)(Wp + kn); \
      if (aact) AREG = *(const float2*)(Apt + kn); } \
    { int kx = ((S) + 1 < NSTEP ? (S) + 1 : NSTEP - 1) * BK; \
      GLDS2(kx, (BF) ^ 1); } \
    _Pragma("unroll") \
    for (int kk = 0; kk < 2; ++kk) { \
      bf16x8 xf = *(const bf16x8*)&xls[BF][(wv * 16 + l15) * BK + (((kk * 4 + l4) ^ (l15 & 7)) * 8)]; \
      bf16x8 w0 = *(const bf16x8*)&wls[BF][l15][kk * 32 + l4 * 8]; \
      bf16x8 w1 = *(const bf16x8*)&wls[BF][16 + l15][kk * 32 + l4 * 8]; \
      bf16x8 af = *(const bf16x8*)&wls[BF][32 + (l15 >> 3)][kk * 32 + l4 * 8]; \
      accW0 = __builtin_amdgcn_mfma_f32_16x16x32_bf16(xf, w0, accW0, 0, 0, 0); \
      accW1 = __builtin_amdgcn_mfma_f32_16x16x32_bf16(xf, w1, accW1, 0, 0, 0); \
      accY  = __builtin_amdgcn_mfma_f32_16x16x32_bf16(xf, af, accY, 0, 0, 0); \
    } \
  }

__global__ __launch_bounds__(512) void lokr_main(
    const float* __restrict__ W,           // 8192 x 8192
    const float* __restrict__ A,           // 512 x 8192
    const float* __restrict__ Bv,          // 16
    const float* __restrict__ scal,        // 1
    const unsigned short* __restrict__ xb, // x as bf16, 128 x 8192
    float* __restrict__ out)               // 128 x 8192 fp32
{
  __shared__ unsigned short xls[2][M_DIM * BK];   // 2 x 16 KB, XOR-swizzled
  __shared__ unsigned short wls[2][34][72];       // 2 x 4.9 KB, 144B stride

  const int t    = threadIdx.x;
  const int lane = t & 63;
  const int wv   = t >> 6;          // wave 0..7 = m-frag (rows 16wv..16wv+15)
  const int b    = blockIdx.x;      // n-tile: out cols [32b, 32b+32)
  const int l15  = lane & 15;
  const int l4   = lane >> 4;

  const float sB = 2.0f * scal[0] * Bv[l15];

  // W staging: thread t -> W row 32b+(t>>4), float4 chunk t&15 (contiguous)
  const float* Wp  = W + (size_t)(b * BN + (t >> 4)) * K_DIM + (t & 15) * 4;
  const bool  aact = (t < 64);
  const float* Apt = A + (size_t)(2 * b + ((t >> 5) & 1)) * K_DIM + (t & 31) * 2;

  // x glds sources: chunk j of wave covers rows wv*16+j*8+(lane>>3);
  // source 16B-chunk = (lane&7) ^ (row&7)  (involution; reader re-XORs)
  const int xr0 = wv * 16 + (lane >> 3);
  const int xr1 = xr0 + 8;
  const int xc  = lane & 7;
  const unsigned short* xs0 = xb + (size_t)xr0 * K_DIM + ((xc ^ (xr0 & 7)) * 8);
  const unsigned short* xs1 = xb + (size_t)xr1 * K_DIM + ((xc ^ (xr1 & 7)) * 8);

  f32x4 accW0 = {0.f, 0.f, 0.f, 0.f};
  f32x4 accW1 = {0.f, 0.f, 0.f, 0.f};
  f32x4 accY  = {0.f, 0.f, 0.f, 0.f};

  // ---- prologue: W regs 2-deep, x tile 0 in flight ----
  float4 wA = *(const float4*)(Wp);
  float4 wB = *(const float4*)(Wp + BK);
  float2 aA = {0.f, 0.f}, aB = {0.f, 0.f};
  if (aact) { aA = *(const float2*)(Apt); aB = *(const float2*)(Apt + BK); }
  GLDS2(0, 0);

  for (int s2 = 0; s2 < NSTEP; s2 += 2) {
    ITER(s2,     0, wA, aA);
    ITER(s2 + 1, 1, wB, aB);
  }

  // ---- epilogue: fold y2, direct store (no cross-wave reduction) ----
  // C-layout: m = wv*16 + l4*4 + r, col = 32b + nf*16 + l15.
  // accY cols 0-7 = y2[m,2b], cols 8-15 = y2[m,2b+1]; col group nf -> nf<<3.
  const size_t ob = (size_t)(wv * 16 + l4 * 4) * N_DIM + (size_t)b * BN + l15;
#pragma unroll
  for (int nf = 0; nf < 2; ++nf) {
    f32x4 aw = nf ? accW1 : accW0;
#pragma unroll
    for (int r = 0; r < 4; ++r) {
      float y2v = __shfl(accY[r], (lane & 48) | (nf << 3), 64);
      out[ob + (size_t)r * N_DIM + nf * 16] = aw[r] + sB * y2v;
    }
  }
}

extern "C" void kernel_launch(void* const* d_in, const int* in_sizes, int n_in,
                              void* d_out, int out_size, void* d_ws, size_t ws_size,
                              hipStream_t stream) {
  const float* x    = (const float*)d_in[0];   // 128 x 8192
  const float* W    = (const float*)d_in[1];   // 8192 x 8192
  const float* A    = (const float*)d_in[2];   // 512 x 8192
  const float* Bv   = (const float*)d_in[3];   // 16
  const float* scal = (const float*)d_in[4];   // 1
  float* out = (float*)d_out;

  // ws layout: [0, 2MB) x as bf16
  unsigned short* xb = (unsigned short*)d_ws;

  convert_x_kernel<<<512, 256, 0, stream>>>((const float4*)x, (ushort4*)xb);
  lokr_main<<<N_DIM / BN, 512, 0, stream>>>(W, A, Bv, scal, xb, out);
}